// Round 3
// baseline (103.550 us; speedup 1.0000x reference)
//
#include <hip/hip_runtime.h>

typedef float f32x2 __attribute__((ext_vector_type(2)));

#define B_    4
#define NPTS  8192          // N == M == 8192
#define NJ    16            // j-chunks per direction
#define JC    (NPTS / NJ)   // 512 dst points per chunk
#define JP    (JC / 2)      // 256 dst pairs per chunk
#define PT    4             // src points per thread
#define BLK   256
#define ITILE (BLK * PT)    // 1024 src points per block
#define TOT   (B_ * NPTS)   // 32768

// ws layout: partial float[2 * B_ * NJ * NPTS] = 4 MiB @ offset 0
// layout index: ((dir*B_ + b)*NJ + jchunk)*NPTS + i   (coalesced write AND read)

// Fused transform+stage+min kernel.
// grid: (NPTS/ITILE, NJ, 2*B_) = (8,16,8) = 1024 blocks -> 4 blocks/CU,
// 16 waves/CU (Round-1-proven latency hiding; PT=8/512 blocks stalled at 56% busy).
__global__ __launch_bounds__(BLK) void pass1_kernel(
    const float* __restrict__ pred, const float* __restrict__ gt,
    float* __restrict__ partial) {
  // dst chunk, transformed and pre-paired:
  // lds[jp][0] = (-2x0, -2x1, -2y0, -2y1), lds[jp][1] = (-2z0, -2z1, w0, w1)
  __shared__ float4 lds[JP][2];

  const int zb  = blockIdx.z;
  const int dir = zb >> 2;          // 0: pred->gt, 1: gt->pred
  const int b   = zb & 3;
  const float* src = dir ? gt   : pred;
  const float* dst = dir ? pred : gt;

  const int tid   = threadIdx.x;
  const int jbase = blockIdx.y * JC;
  const int ibase = blockIdx.x * ITILE;

  // Stage + transform one dst pair per thread (JP == BLK).
  {
    const float* g = dst + ((size_t)b * NPTS + jbase + 2 * tid) * 3;
    const float x0 = g[0], y0 = g[1], z0 = g[2];
    const float x1 = g[3], y1 = g[4], z1 = g[5];
    lds[tid][0] = make_float4(-2.f * x0, -2.f * x1, -2.f * y0, -2.f * y1);
    lds[tid][1] = make_float4(-2.f * z0, -2.f * z1,
                              fmaf(x0, x0, fmaf(y0, y0, z0 * z0)),
                              fmaf(x1, x1, fmaf(y1, y1, z1 * z1)));
  }

  // Load PT src points; keep splatted f32x2 copies (loop-invariant, hoisted).
  f32x2 px[PT], py[PT], pz[PT];
  float m[PT];
#pragma unroll
  for (int p = 0; p < PT; ++p) {
    const int i = ibase + p * BLK + tid;
    const float* s = src + ((size_t)b * NPTS + i) * 3;
    px[p] = (f32x2){s[0], s[0]};
    py[p] = (f32x2){s[1], s[1]};
    pz[p] = (f32x2){s[2], s[2]};
    m[p] = 1e30f;
  }
  __syncthreads();

#pragma unroll 4
  for (int jp = 0; jp < JP; ++jp) {
    const float4 c0 = lds[jp][0];   // x0 x1 y0 y1 (uniform -> broadcast read)
    const float4 c1 = lds[jp][1];   // z0 z1 w0 w1
    const f32x2 gx = {c0.x, c0.y};
    const f32x2 gy = {c0.z, c0.w};
    const f32x2 gz = {c1.x, c1.y};
    const f32x2 gw = {c1.z, c1.w};
#pragma unroll
    for (int p = 0; p < PT; ++p) {
      f32x2 t = __builtin_elementwise_fma(px[p], gx, gw);   // v_pk_fma_f32
      t = __builtin_elementwise_fma(py[p], gy, t);
      t = __builtin_elementwise_fma(pz[p], gz, t);
      m[p] = fminf(fminf(t.x, t.y), m[p]);                  // v_min3_f32
    }
  }

#pragma unroll
  for (int p = 0; p < PT; ++p) {
    const int i = ibase + p * BLK + tid;
    partial[((size_t)(dir * B_ + b) * NJ + blockIdx.y) * NPTS + i] = m[p];
  }
}

// Per point: min over NJ chunk-partials (coalesced), add ||x||^2,
// block-reduce, one scaled atomic per block into d_out.
__global__ __launch_bounds__(256) void pass2_kernel(
    const float* __restrict__ pred, const float* __restrict__ gt,
    const float* __restrict__ partial, float* __restrict__ out) {
  const int gid = blockIdx.x * 256 + threadIdx.x;
  const int dir = gid >= TOT;         // blocks never straddle (TOT % 256 == 0)
  const int idx = dir ? gid - TOT : gid;   // = b*NPTS + i
  const float* src = dir ? gt : pred;
  const int b = idx >> 13;            // NPTS == 8192
  const int i = idx & (NPTS - 1);

  const float* p = partial + ((size_t)(dir * B_ + b) * NJ) * NPTS + i;
  float m = 1e30f;
#pragma unroll
  for (int k = 0; k < NJ; ++k) m = fminf(m, p[(size_t)k * NPTS]);

  const float x = src[3 * idx + 0], y = src[3 * idx + 1], z = src[3 * idx + 2];
  const float dist = fmaf(x, x, fmaf(y, y, z * z)) + m;

  __shared__ float red[256];
  const int tid = threadIdx.x;
  red[tid] = dist;
  __syncthreads();
  for (int s = 128; s > 0; s >>= 1) {
    if (tid < s) red[tid] += red[tid + s];
    __syncthreads();
  }
  if (tid == 0) atomicAdd(out, red[0] * (1.0f / TOT));
}

extern "C" void kernel_launch(void* const* d_in, const int* in_sizes, int n_in,
                              void* d_out, int out_size, void* d_ws, size_t ws_size,
                              hipStream_t stream) {
  const float* pred = (const float*)d_in[0];
  const float* gt   = (const float*)d_in[1];
  float* partial = (float*)d_ws;
  float* out = (float*)d_out;

  hipMemsetAsync(out, 0, out_size * sizeof(float), stream);

  dim3 g1(NPTS / ITILE, NJ, 2 * B_);   // (8, 16, 8) = 1024 blocks
  pass1_kernel<<<g1, BLK, 0, stream>>>(pred, gt, partial);

  pass2_kernel<<<(2 * TOT) / 256, 256, 0, stream>>>(pred, gt, partial, out);
}

// Round 4
// 100.735 us; speedup vs baseline: 1.0279x; 1.0279x over previous
//
#include <hip/hip_runtime.h>

typedef float f32x2 __attribute__((ext_vector_type(2)));

#define B_    4
#define NPTS  8192          // N == M == 8192
#define NJ    64            // j-chunks per direction
#define JC    (NPTS / NJ)   // 128 dst points per chunk
#define JP    (JC / 2)      // 64 dst pairs per chunk
#define PT    16            // src points per thread
#define BLK   256
#define ITILE (BLK * PT)    // 4096 src points per block
#define TOT   (B_ * NPTS)   // 32768

// ws layout: slots uint32[2*TOT] = 256 KiB @ 0, memset to 0xFF (= +max in
// the order-preserving float->uint map) before every launch.
// Monotone map: u = bits ^ ((bits>>31) | 0x80000000)  (unsigned compare == float compare)

// Fused transform + stage + min + fold-xx + atomicMin kernel.
// grid: (NPTS/ITILE, NJ, 2*B_) = (2, 64, 8) = 1024 blocks -> 4 blocks/CU,
// 16 waves/CU. Inner loop forced to v_pk_fma_f32 / v_min3_f32 (2 inst/eval);
// PT=16 cuts ds_read_b128 count 4x vs R3 (LDS was the real 50us limiter).
__global__ __launch_bounds__(BLK) void pass1_kernel(
    const float* __restrict__ pred, const float* __restrict__ gt,
    unsigned* __restrict__ slots) {
  // lds[jp][0] = (-2x0, -2x1, -2y0, -2y1), lds[jp][1] = (-2z0, -2z1, w0, w1)
  __shared__ float4 lds[JP][2];

  const int zb  = blockIdx.z;
  const int dir = zb >> 2;          // 0: pred->gt, 1: gt->pred
  const int b   = zb & 3;
  const float* src = dir ? gt   : pred;
  const float* dst = dir ? pred : gt;

  const int tid   = threadIdx.x;
  const int jbase = blockIdx.y * JC;
  const int ibase = blockIdx.x * ITILE;

  // Stage + transform one dst pair per thread (JP == 64, first wave only).
  if (tid < JP) {
    const float* g = dst + ((size_t)b * NPTS + jbase + 2 * tid) * 3;
    const float x0 = g[0], y0 = g[1], z0 = g[2];
    const float x1 = g[3], y1 = g[4], z1 = g[5];
    lds[tid][0] = make_float4(-2.f * x0, -2.f * x1, -2.f * y0, -2.f * y1);
    lds[tid][1] = make_float4(-2.f * z0, -2.f * z1,
                              fmaf(x0, x0, fmaf(y0, y0, z0 * z0)),
                              fmaf(x1, x1, fmaf(y1, y1, z1 * z1)));
  }

  // PT src points, splatted into f32x2 lanes (hoisted, loop-invariant).
  f32x2 px[PT], py[PT], pz[PT];
  float m[PT];
#pragma unroll
  for (int p = 0; p < PT; ++p) {
    const int i = ibase + p * BLK + tid;
    const float* s = src + ((size_t)b * NPTS + i) * 3;
    px[p] = (f32x2){s[0], s[0]};
    py[p] = (f32x2){s[1], s[1]};
    pz[p] = (f32x2){s[2], s[2]};
    m[p] = 1e30f;
  }
  __syncthreads();

#pragma unroll 2
  for (int jp = 0; jp < JP; ++jp) {
    const float4 c0 = lds[jp][0];   // x0 x1 y0 y1 (wave-uniform broadcast)
    const float4 c1 = lds[jp][1];   // z0 z1 w0 w1
    const f32x2 gx = {c0.x, c0.y};
    const f32x2 gy = {c0.z, c0.w};
    const f32x2 gz = {c1.x, c1.y};
    const f32x2 gw = {c1.z, c1.w};
#pragma unroll
    for (int p = 0; p < PT; ++p) {
      f32x2 t;
      // d(pair) = ||g||^2 - 2<p,g>, two dst points per instruction.
      asm("v_pk_fma_f32 %0, %1, %2, %3" : "=v"(t) : "v"(px[p]), "v"(gx), "v"(gw));
      asm("v_pk_fma_f32 %0, %1, %2, %3" : "=v"(t) : "v"(py[p]), "v"(gy), "v"(t));
      asm("v_pk_fma_f32 %0, %1, %2, %3" : "=v"(t) : "v"(pz[p]), "v"(gz), "v"(t));
      asm("v_min3_f32 %0, %1, %2, %3" : "=v"(m[p]) : "v"(t.x), "v"(t.y), "v"(m[p]));
    }
  }

  // Epilogue: dist = ||p||^2 + min_chunk; order-preserving uint map; atomicMin.
#pragma unroll
  for (int p = 0; p < PT; ++p) {
    const int i = ibase + p * BLK + tid;
    const float x = px[p].x, y = py[p].x, z = pz[p].x;
    const float d = fmaf(x, x, fmaf(y, y, z * z)) + m[p];
    const int   bi = __float_as_int(d);
    const unsigned u = (unsigned)bi ^ (unsigned)((bi >> 31) | 0x80000000);
    atomicMin(&slots[(size_t)(dir * B_ + b) * NPTS + i], u);  // coalesced addrs
  }
}

// Sweep 2*TOT slots, map back to float, reduce, one atomic per block.
// grid: 32 blocks x 256 threads x 8 slots (stride-8192 -> coalesced).
__global__ __launch_bounds__(256) void pass2_kernel(
    const unsigned* __restrict__ slots, float* __restrict__ out) {
  const int gid = blockIdx.x * 256 + threadIdx.x;   // 8192 threads
  float s = 0.f;
#pragma unroll
  for (int k = 0; k < 8; ++k) {
    const unsigned u = slots[gid + k * 8192];
    const int bi = (u & 0x80000000u) ? (int)(u ^ 0x80000000u) : (int)~u;
    s += __int_as_float(bi);
  }
  __shared__ float red[256];
  const int tid = threadIdx.x;
  red[tid] = s;
  __syncthreads();
  for (int st = 128; st > 0; st >>= 1) {
    if (tid < st) red[tid] += red[tid + st];
    __syncthreads();
  }
  if (tid == 0) atomicAdd(out, red[0] * (1.0f / TOT));
}

extern "C" void kernel_launch(void* const* d_in, const int* in_sizes, int n_in,
                              void* d_out, int out_size, void* d_ws, size_t ws_size,
                              hipStream_t stream) {
  const float* pred = (const float*)d_in[0];
  const float* gt   = (const float*)d_in[1];
  unsigned* slots = (unsigned*)d_ws;
  float* out = (float*)d_out;

  hipMemsetAsync(slots, 0xFF, (size_t)2 * TOT * sizeof(unsigned), stream);
  hipMemsetAsync(out, 0, out_size * sizeof(float), stream);

  dim3 g1(NPTS / ITILE, NJ, 2 * B_);   // (2, 64, 8) = 1024 blocks
  pass1_kernel<<<g1, BLK, 0, stream>>>(pred, gt, slots);

  pass2_kernel<<<(2 * TOT) / (256 * 8), 256, 0, stream>>>(slots, out);
}

// Round 5
// 98.972 us; speedup vs baseline: 1.0463x; 1.0178x over previous
//
#include <hip/hip_runtime.h>

#define B_    4
#define NPTS  8192          // N == M == 8192
#define NJ    64            // j-chunks per direction
#define JC    (NPTS / NJ)   // 128 dst points per chunk
#define JP    (JC / 2)      // 64 dst pairs per chunk
#define PT    8             // src points per thread
#define BLK   256
#define ITILE (BLK * PT)    // 2048 src points per block
#define TOT   (B_ * NPTS)   // 32768

// ws: slots uint32[2*TOT] = 256 KiB @ 0, memset 0xFF (=+max in monotone map).
// Monotone map: u = bits ^ ((bits>>31) | 0x80000000); uint cmp == float cmp.

// Fused transform + stage + min + fold-xx + atomicMin.
// grid (NPTS/ITILE, NJ, 2*B_) = (4,64,8) = 2048 blocks -> 8 blocks/CU.
// Scalar fma + forced v_min3_f32: 14 cyc/pair — same VALU cycles as R4's
// pk_fma (no packed-f32 doubling on gfx950) but ~60 fewer VGPRs (no f32x2
// splats) -> 7 waves/SIMD, which is what R4 lacked (62% busy at VGPR=124).
__global__ __launch_bounds__(BLK, 7) void pass1_kernel(
    const float* __restrict__ pred, const float* __restrict__ gt,
    unsigned* __restrict__ slots) {
  __shared__ float4 lds[JC];   // per dst point: (-2x, -2y, -2z, ||g||^2)

  const int zb  = blockIdx.z;
  const int dir = zb >> 2;          // 0: pred->gt, 1: gt->pred
  const int b   = zb & 3;
  const float* src = dir ? gt   : pred;
  const float* dst = dir ? pred : gt;

  const int tid   = threadIdx.x;
  const int jbase = blockIdx.y * JC;
  const int ibase = blockIdx.x * ITILE;

  // Stage + transform one dst point per thread (JC == 128, first 2 waves).
  if (tid < JC) {
    const float* g = dst + ((size_t)b * NPTS + jbase + tid) * 3;
    const float x = g[0], y = g[1], z = g[2];
    lds[tid] = make_float4(-2.f * x, -2.f * y, -2.f * z,
                           fmaf(x, x, fmaf(y, y, z * z)));
  }

  float px[PT], py[PT], pz[PT], m[PT];
#pragma unroll
  for (int p = 0; p < PT; ++p) {
    const int i = ibase + p * BLK + tid;
    const float* s = src + ((size_t)b * NPTS + i) * 3;
    px[p] = s[0]; py[p] = s[1]; pz[p] = s[2];
    m[p] = 1e30f;
  }
  __syncthreads();

#pragma unroll 4
  for (int jp = 0; jp < JP; ++jp) {
    const float4 g0 = lds[2 * jp + 0];   // wave-uniform -> broadcast, no conflict
    const float4 g1 = lds[2 * jp + 1];
#pragma unroll
    for (int p = 0; p < PT; ++p) {
      const float t0 = fmaf(pz[p], g0.z, fmaf(py[p], g0.y, fmaf(px[p], g0.x, g0.w)));
      const float t1 = fmaf(pz[p], g1.z, fmaf(py[p], g1.y, fmaf(px[p], g1.x, g1.w)));
      asm("v_min3_f32 %0, %1, %2, %3"
          : "=v"(m[p]) : "v"(t0), "v"(t1), "v"(m[p]));
    }
  }

  // dist = ||p||^2 + min_chunk; monotone uint map; one atomicMin per (p,i).
#pragma unroll
  for (int p = 0; p < PT; ++p) {
    const int i = ibase + p * BLK + tid;
    const float d = fmaf(px[p], px[p], fmaf(py[p], py[p], pz[p] * pz[p])) + m[p];
    const int   bi = __float_as_int(d);
    const unsigned u = (unsigned)bi ^ (unsigned)((bi >> 31) | 0x80000000);
    atomicMin(&slots[(size_t)(dir * B_ + b) * NPTS + i], u);  // coalesced
  }
}

// Sweep 2*TOT slots, decode, reduce, one atomic per block.
__global__ __launch_bounds__(256) void pass2_kernel(
    const unsigned* __restrict__ slots, float* __restrict__ out) {
  const int gid = blockIdx.x * 256 + threadIdx.x;   // 8192 threads
  float s = 0.f;
#pragma unroll
  for (int k = 0; k < 8; ++k) {
    const unsigned u = slots[gid + k * 8192];
    const int bi = (u & 0x80000000u) ? (int)(u ^ 0x80000000u) : (int)~u;
    s += __int_as_float(bi);
  }
  __shared__ float red[256];
  const int tid = threadIdx.x;
  red[tid] = s;
  __syncthreads();
  for (int st = 128; st > 0; st >>= 1) {
    if (tid < st) red[tid] += red[tid + st];
    __syncthreads();
  }
  if (tid == 0) atomicAdd(out, red[0] * (1.0f / TOT));
}

extern "C" void kernel_launch(void* const* d_in, const int* in_sizes, int n_in,
                              void* d_out, int out_size, void* d_ws, size_t ws_size,
                              hipStream_t stream) {
  const float* pred = (const float*)d_in[0];
  const float* gt   = (const float*)d_in[1];
  unsigned* slots = (unsigned*)d_ws;
  float* out = (float*)d_out;

  hipMemsetAsync(slots, 0xFF, (size_t)2 * TOT * sizeof(unsigned), stream);
  hipMemsetAsync(out, 0, out_size * sizeof(float), stream);

  dim3 g1(NPTS / ITILE, NJ, 2 * B_);   // (4, 64, 8) = 2048 blocks
  pass1_kernel<<<g1, BLK, 0, stream>>>(pred, gt, slots);

  pass2_kernel<<<(2 * TOT) / (256 * 8), 256, 0, stream>>>(slots, out);
}